// Round 1
// baseline (15834.854 us; speedup 1.0000x reference)
//
#include <hip/hip_runtime.h>

#define DF 128

// ---------------- CSR build ----------------

__global__ void count_kernel(const int* __restrict__ dst, int* __restrict__ cnt, int E) {
  int i = blockIdx.x * blockDim.x + threadIdx.x;
  if (i < E) atomicAdd(&cnt[dst[i]], 1);
}

// 1024 elements per block (256 threads x 4), local exclusive scan + block sums
__global__ void scan1_kernel(const int* __restrict__ cnt, int* __restrict__ excl,
                             int* __restrict__ bsums, int n) {
  __shared__ int wsum[4];
  int t = threadIdx.x;
  int base = blockIdx.x * 1024 + t * 4;
  int v[4]; int s = 0;
#pragma unroll
  for (int i = 0; i < 4; i++) { int d = (base + i < n) ? cnt[base + i] : 0; v[i] = s; s += d; }
  int lane = t & 63, w = t >> 6;
  int sc = s;
#pragma unroll
  for (int off = 1; off < 64; off <<= 1) { int o = __shfl_up(sc, off); if (lane >= off) sc += o; }
  if (lane == 63) wsum[w] = sc;
  __syncthreads();
  int woff = 0;
  for (int i = 0; i < w; i++) woff += wsum[i];
  int toff = woff + (sc - s);
#pragma unroll
  for (int i = 0; i < 4; i++) if (base + i < n) excl[base + i] = toff + v[i];
  if (t == 255) bsums[blockIdx.x] = woff + sc;
}

__global__ void scan2_kernel(int* bsums, int nb) {
  if (threadIdx.x == 0 && blockIdx.x == 0) {
    int s = 0;
    for (int i = 0; i < nb; i++) { int d = bsums[i]; bsums[i] = s; s += d; }
  }
}

__global__ void scan3_kernel(int* __restrict__ rowptr, const int* __restrict__ bsums,
                             int* __restrict__ cursor, int n, int E) {
  int i = blockIdx.x * blockDim.x + threadIdx.x;
  if (i < n) {
    int v = rowptr[i] + bsums[i >> 10];
    rowptr[i] = v;
    cursor[i] = v;
  }
  if (i == 0) rowptr[n] = E;
}

__global__ void scatter_kernel(const int* __restrict__ src, const int* __restrict__ dst,
                               int* __restrict__ cursor, int* __restrict__ csr, int E) {
  int i = blockIdx.x * blockDim.x + threadIdx.x;
  if (i < E) {
    int pos = atomicAdd(&cursor[dst[i]], 1);
    csr[pos] = src[i];
  }
}

// ---------------- scatter-mean as CSR gather: one wave per node ----------------
__global__ void aggregate_kernel(const float* __restrict__ x, const int* __restrict__ rowptr,
                                 const int* __restrict__ csr, float* __restrict__ out, int n) {
  int gw = (blockIdx.x * blockDim.x + threadIdx.x) >> 6;
  int lane = threadIdx.x & 63;
  if (gw >= n) return;
  int beg = rowptr[gw], end = rowptr[gw + 1];
  const float2* x2 = (const float2*)x;
  float2 acc = {0.f, 0.f};
  for (int e = beg; e < end; ++e) {
    int s = csr[e];
    float2 v = x2[(size_t)s * 64 + lane];
    acc.x += v.x; acc.y += v.y;
  }
  int deg = end - beg;
  float2 r;
  if (deg > 0) { float inv = 1.0f / (float)deg; r.x = acc.x * inv; r.y = acc.y * inv; }
  else r = x2[(size_t)gw * 64 + lane];
  ((float2*)out)[(size_t)gw * 64 + lane] = r;
}

// ---------------- GEMM 128x128 + bias + tanh: lane-per-node, W in LDS ----------------
__global__ __launch_bounds__(256, 2) void gemm_tanh_kernel(const float* __restrict__ in,
    const float* __restrict__ W, const float* __restrict__ bias,
    float* __restrict__ out, int n) {
  __shared__ float Wl[DF * DF];
  __shared__ float bl[DF];
  {
    const float4* W4 = (const float4*)W;
    float4* Wl4 = (float4*)Wl;
    for (int i = threadIdx.x; i < DF * DF / 4; i += 256) Wl4[i] = W4[i];
    if (threadIdx.x < DF) bl[threadIdx.x] = bias[threadIdx.x];
  }
  __syncthreads();
  int lane = threadIdx.x & 63;
  int gwave = (blockIdx.x * 256 + threadIdx.x) >> 6;
  int nwaves = gridDim.x * 4;
  int ntiles = (n + 63) >> 6;
  for (int tile = gwave; tile < ntiles; tile += nwaves) {
    int node = tile * 64 + lane;
    int nc = node < n ? node : n - 1;
    float a[DF];
    const float4* ar = (const float4*)(in + (size_t)nc * DF);
#pragma unroll
    for (int i = 0; i < DF / 4; i++) {
      float4 v = ar[i];
      a[4 * i] = v.x; a[4 * i + 1] = v.y; a[4 * i + 2] = v.z; a[4 * i + 3] = v.w;
    }
    float* orow = out + (size_t)nc * DF;
#pragma unroll 1
    for (int j = 0; j < DF; j += 8) {
      float acc[8];
#pragma unroll
      for (int q = 0; q < 8; q++) acc[q] = bl[j + q];
#pragma unroll
      for (int k = 0; k < DF; k++) {
        float4 w0 = *(const float4*)&Wl[k * DF + j];
        float4 w1 = *(const float4*)&Wl[k * DF + j + 4];
        float ak = a[k];
        acc[0] += ak * w0.x; acc[1] += ak * w0.y; acc[2] += ak * w0.z; acc[3] += ak * w0.w;
        acc[4] += ak * w1.x; acc[5] += ak * w1.y; acc[6] += ak * w1.z; acc[7] += ak * w1.w;
      }
      if (node < n) {
#pragma unroll
        for (int q = 0; q < 8; q++) orow[j + q] = tanhf(acc[q]);
      }
    }
  }
}

// ---------------- head: 128x10 + bias ----------------
__global__ __launch_bounds__(256, 2) void head_kernel(const float* __restrict__ in,
    const float* __restrict__ W, const float* __restrict__ bias,
    float* __restrict__ out, int n) {
  __shared__ float Wl[DF * 10];
  __shared__ float bl[10];
  for (int i = threadIdx.x; i < DF * 10; i += 256) Wl[i] = W[i];
  if (threadIdx.x < 10) bl[threadIdx.x] = bias[threadIdx.x];
  __syncthreads();
  int lane = threadIdx.x & 63;
  int gwave = (blockIdx.x * 256 + threadIdx.x) >> 6;
  int nwaves = gridDim.x * 4;
  int ntiles = (n + 63) >> 6;
  for (int tile = gwave; tile < ntiles; tile += nwaves) {
    int node = tile * 64 + lane;
    int nc = node < n ? node : n - 1;
    float a[DF];
    const float4* ar = (const float4*)(in + (size_t)nc * DF);
#pragma unroll
    for (int i = 0; i < DF / 4; i++) {
      float4 v = ar[i];
      a[4 * i] = v.x; a[4 * i + 1] = v.y; a[4 * i + 2] = v.z; a[4 * i + 3] = v.w;
    }
    float acc[10];
#pragma unroll
    for (int q = 0; q < 10; q++) acc[q] = bl[q];
#pragma unroll
    for (int k = 0; k < DF; k++) {
      float ak = a[k];
#pragma unroll
      for (int q = 0; q < 10; q++) acc[q] += ak * Wl[k * 10 + q];
    }
    if (node < n) {
#pragma unroll
      for (int q = 0; q < 10; q++) out[(size_t)node * 10 + q] = acc[q];
    }
  }
}

extern "C" void kernel_launch(void* const* d_in, const int* in_sizes, int n_in,
                              void* d_out, int out_size, void* d_ws, size_t ws_size,
                              hipStream_t stream) {
  const float* x    = (const float*)d_in[0];
  const int*   esrc = (const int*)d_in[1];
  const int*   edst = (const int*)d_in[2];
  const float* W1   = (const float*)d_in[3];
  const float* b1   = (const float*)d_in[4];
  const float* W2   = (const float*)d_in[5];
  const float* b2   = (const float*)d_in[6];
  const float* W3   = (const float*)d_in[7];
  const float* b3   = (const float*)d_in[8];
  float* out = (float*)d_out;

  const int N = in_sizes[0] / DF;   // 100000
  const int E = in_sizes[1];        // 1600000

  // workspace layout (~110 MB):
  // rowptr[N+1] | cursor[N] | bsums[1024] | csr[E] | bufA[N*128] f32 | bufB[N*128] f32
  char* ws = (char*)d_ws;
  int* rowptr = (int*)ws;
  int* cursor = rowptr + (N + 1);
  int* bsums  = cursor + N;
  int* csr    = bsums + 1024;
  size_t ioff = (size_t)((char*)(csr + E) - ws);
  ioff = (ioff + 255) & ~(size_t)255;
  float* bufA = (float*)(ws + ioff);
  float* bufB = bufA + (size_t)N * DF;

  const int nb = (N + 1023) / 1024;

  hipMemsetAsync(cursor, 0, (size_t)N * sizeof(int), stream);
  count_kernel<<<(E + 255) / 256, 256, 0, stream>>>(edst, cursor, E);
  scan1_kernel<<<nb, 256, 0, stream>>>(cursor, rowptr, bsums, N);
  scan2_kernel<<<1, 64, 0, stream>>>(bsums, nb);
  scan3_kernel<<<(N + 255) / 256, 256, 0, stream>>>(rowptr, bsums, cursor, N, E);
  scatter_kernel<<<(E + 255) / 256, 256, 0, stream>>>(esrc, edst, cursor, csr, E);

  int agg_blocks = (N * 64 + 255) / 256;           // one wave per node
  int ntiles = (N + 63) / 64;
  int gemm_blocks = (ntiles + 3) / 4;

  // layer 1
  aggregate_kernel<<<agg_blocks, 256, 0, stream>>>(x, rowptr, csr, bufA, N);
  gemm_tanh_kernel<<<gemm_blocks, 256, 0, stream>>>(bufA, W1, b1, bufB, N);
  // layer 2
  aggregate_kernel<<<agg_blocks, 256, 0, stream>>>(bufB, rowptr, csr, bufA, N);
  gemm_tanh_kernel<<<gemm_blocks, 256, 0, stream>>>(bufA, W2, b2, bufB, N);
  // head
  head_kernel<<<gemm_blocks, 256, 0, stream>>>(bufB, W3, b3, out, N);
}

// Round 2
// 676.889 us; speedup vs baseline: 23.3936x; 23.3936x over previous
//
#include <hip/hip_runtime.h>

#define DF 128

// ---------------- CSR build ----------------

__global__ void count_kernel(const int* __restrict__ dst, int* __restrict__ cnt, int E) {
  int i = blockIdx.x * blockDim.x + threadIdx.x;
  if (i < E) atomicAdd(&cnt[dst[i]], 1);
}

// 1024 elements per block (256 threads x 4), local exclusive scan + block sums
__global__ void scan1_kernel(const int* __restrict__ cnt, int* __restrict__ excl,
                             int* __restrict__ bsums, int n) {
  __shared__ int wsum[4];
  int t = threadIdx.x;
  int base = blockIdx.x * 1024 + t * 4;
  int v[4]; int s = 0;
#pragma unroll
  for (int i = 0; i < 4; i++) { int d = (base + i < n) ? cnt[base + i] : 0; v[i] = s; s += d; }
  int lane = t & 63, w = t >> 6;
  int sc = s;
#pragma unroll
  for (int off = 1; off < 64; off <<= 1) { int o = __shfl_up(sc, off); if (lane >= off) sc += o; }
  if (lane == 63) wsum[w] = sc;
  __syncthreads();
  int woff = 0;
  for (int i = 0; i < w; i++) woff += wsum[i];
  int toff = woff + (sc - s);
#pragma unroll
  for (int i = 0; i < 4; i++) if (base + i < n) excl[base + i] = toff + v[i];
  if (t == 255) bsums[blockIdx.x] = woff + sc;
}

__global__ void scan2_kernel(int* bsums, int nb) {
  if (threadIdx.x == 0 && blockIdx.x == 0) {
    int s = 0;
    for (int i = 0; i < nb; i++) { int d = bsums[i]; bsums[i] = s; s += d; }
  }
}

__global__ void scan3_kernel(int* __restrict__ rowptr, const int* __restrict__ bsums,
                             int* __restrict__ cursor, int n, int E) {
  int i = blockIdx.x * blockDim.x + threadIdx.x;
  if (i < n) {
    int v = rowptr[i] + bsums[i >> 10];
    rowptr[i] = v;
    cursor[i] = v;
  }
  if (i == 0) rowptr[n] = E;
}

__global__ void scatter_kernel(const int* __restrict__ src, const int* __restrict__ dst,
                               int* __restrict__ cursor, int* __restrict__ csr, int E) {
  int i = blockIdx.x * blockDim.x + threadIdx.x;
  if (i < E) {
    int pos = atomicAdd(&cursor[dst[i]], 1);
    csr[pos] = src[i];
  }
}

// ---------------- scatter-mean as CSR gather: one wave per node ----------------
__global__ void aggregate_kernel(const float* __restrict__ x, const int* __restrict__ rowptr,
                                 const int* __restrict__ csr, float* __restrict__ out, int n) {
  int gw = (blockIdx.x * blockDim.x + threadIdx.x) >> 6;
  int lane = threadIdx.x & 63;
  if (gw >= n) return;
  int beg = rowptr[gw], end = rowptr[gw + 1];
  const float2* x2 = (const float2*)x;
  float2 acc = {0.f, 0.f};
  for (int e = beg; e < end; ++e) {
    int s = csr[e];
    float2 v = x2[(size_t)s * 64 + lane];
    acc.x += v.x; acc.y += v.y;
  }
  int deg = end - beg;
  float2 r;
  if (deg > 0) { float inv = 1.0f / (float)deg; r.x = acc.x * inv; r.y = acc.y * inv; }
  else r = x2[(size_t)gw * 64 + lane];
  ((float2*)out)[(size_t)gw * 64 + lane] = r;
}

// ---------------- GEMM [n x 128] @ [128 x 128] + bias + tanh ----------------
// Block: 64 nodes x 64 cols, K=128 fully staged in LDS.
// Thread (tx,ty): 4 nodes x 4 cols, 16 acc regs -> no spill.
// As padded to 132 floats/row: compute reads are 2-way bank (free).
__global__ __launch_bounds__(256) void gemm_tanh_kernel(const float* __restrict__ in,
    const float* __restrict__ W, const float* __restrict__ bias,
    float* __restrict__ out, int n) {
  __shared__ float As[64][132];
  __shared__ float Ws[128][64];
  __shared__ float bs[64];
  int tid = threadIdx.x;
  int tm = blockIdx.x >> 1;          // node tile
  int tn = blockIdx.x & 1;           // column half (0 or 1)
  int node0 = tm * 64;

  // stage A tile: 64 rows x 32 float4 (coalesced)
  for (int i = tid; i < 64 * 32; i += 256) {
    int r = i >> 5, c = i & 31;
    int node = node0 + r; if (node >= n) node = n - 1;
    float4 v = ((const float4*)(in + (size_t)node * DF))[c];
    *(float4*)&As[r][4 * c] = v;
  }
  // stage W tile: 128 rows x 16 float4 (cols tn*64 .. +63)
  for (int i = tid; i < 128 * 16; i += 256) {
    int r = i >> 4, c = i & 15;
    float4 v = ((const float4*)(W + (size_t)r * DF + tn * 64))[c];
    *(float4*)&Ws[r][4 * c] = v;
  }
  if (tid < 64) bs[tid] = bias[tn * 64 + tid];
  __syncthreads();

  int tx = tid & 15, ty = tid >> 4;
  float acc[4][4];
  {
    float4 bv = *(const float4*)&bs[4 * tx];
#pragma unroll
    for (int i = 0; i < 4; i++) { acc[i][0] = bv.x; acc[i][1] = bv.y; acc[i][2] = bv.z; acc[i][3] = bv.w; }
  }

#pragma unroll 8
  for (int kb = 0; kb < 32; ++kb) {
    float4 a[4], w[4];
#pragma unroll
    for (int i = 0; i < 4; i++) a[i] = *(const float4*)&As[4 * ty + i][4 * kb];
#pragma unroll
    for (int k = 0; k < 4; k++) w[k] = *(const float4*)&Ws[4 * kb + k][4 * tx];
#pragma unroll
    for (int i = 0; i < 4; i++) {
      acc[i][0] += a[i].x * w[0].x; acc[i][1] += a[i].x * w[0].y; acc[i][2] += a[i].x * w[0].z; acc[i][3] += a[i].x * w[0].w;
      acc[i][0] += a[i].y * w[1].x; acc[i][1] += a[i].y * w[1].y; acc[i][2] += a[i].y * w[1].z; acc[i][3] += a[i].y * w[1].w;
      acc[i][0] += a[i].z * w[2].x; acc[i][1] += a[i].z * w[2].y; acc[i][2] += a[i].z * w[2].z; acc[i][3] += a[i].z * w[2].w;
      acc[i][0] += a[i].w * w[3].x; acc[i][1] += a[i].w * w[3].y; acc[i][2] += a[i].w * w[3].z; acc[i][3] += a[i].w * w[3].w;
    }
  }

#pragma unroll
  for (int i = 0; i < 4; i++) {
    int node = node0 + 4 * ty + i;
    if (node < n) {
      float4 r;
      r.x = tanhf(acc[i][0]); r.y = tanhf(acc[i][1]);
      r.z = tanhf(acc[i][2]); r.w = tanhf(acc[i][3]);
      *(float4*)(out + (size_t)node * DF + tn * 64 + 4 * tx) = r;
    }
  }
}

// ---------------- head: [n x 128] @ [128 x 10] + bias ----------------
// thread-per-node, stream A as float4, W broadcast from LDS (same addr across wave = free)
__global__ __launch_bounds__(256) void head_kernel(const float* __restrict__ in,
    const float* __restrict__ W, const float* __restrict__ bias,
    float* __restrict__ out, int n) {
  __shared__ float Wl[DF * 10];
  __shared__ float bl[10];
  for (int i = threadIdx.x; i < DF * 10; i += 256) Wl[i] = W[i];
  if (threadIdx.x < 10) bl[threadIdx.x] = bias[threadIdx.x];
  __syncthreads();
  int node = blockIdx.x * 256 + threadIdx.x;
  if (node >= n) return;
  const float4* ar = (const float4*)(in + (size_t)node * DF);
  float acc[10];
#pragma unroll
  for (int q = 0; q < 10; q++) acc[q] = bl[q];
#pragma unroll 4
  for (int kb = 0; kb < 32; ++kb) {
    float4 v = ar[kb];
    const float* w0 = &Wl[(4 * kb + 0) * 10];
    const float* w1 = &Wl[(4 * kb + 1) * 10];
    const float* w2 = &Wl[(4 * kb + 2) * 10];
    const float* w3 = &Wl[(4 * kb + 3) * 10];
#pragma unroll
    for (int q = 0; q < 10; q++)
      acc[q] += v.x * w0[q] + v.y * w1[q] + v.z * w2[q] + v.w * w3[q];
  }
#pragma unroll
  for (int q = 0; q < 10; q++) out[(size_t)node * 10 + q] = acc[q];
}

extern "C" void kernel_launch(void* const* d_in, const int* in_sizes, int n_in,
                              void* d_out, int out_size, void* d_ws, size_t ws_size,
                              hipStream_t stream) {
  const float* x    = (const float*)d_in[0];
  const int*   esrc = (const int*)d_in[1];
  const int*   edst = (const int*)d_in[2];
  const float* W1   = (const float*)d_in[3];
  const float* b1   = (const float*)d_in[4];
  const float* W2   = (const float*)d_in[5];
  const float* b2   = (const float*)d_in[6];
  const float* W3   = (const float*)d_in[7];
  const float* b3   = (const float*)d_in[8];
  float* out = (float*)d_out;

  const int N = in_sizes[0] / DF;   // 100000
  const int E = in_sizes[1];        // 1600000

  // workspace layout:
  // rowptr[N+1] | cursor[N] | bsums[1024] | csr[E] | bufA[N*128] f32 | bufB[N*128] f32
  char* ws = (char*)d_ws;
  int* rowptr = (int*)ws;
  int* cursor = rowptr + (N + 1);
  int* bsums  = cursor + N;
  int* csr    = bsums + 1024;
  size_t ioff = (size_t)((char*)(csr + E) - ws);
  ioff = (ioff + 255) & ~(size_t)255;
  float* bufA = (float*)(ws + ioff);
  float* bufB = bufA + (size_t)N * DF;

  const int nb = (N + 1023) / 1024;

  hipMemsetAsync(cursor, 0, (size_t)N * sizeof(int), stream);
  count_kernel<<<(E + 255) / 256, 256, 0, stream>>>(edst, cursor, E);
  scan1_kernel<<<nb, 256, 0, stream>>>(cursor, rowptr, bsums, N);
  scan2_kernel<<<1, 64, 0, stream>>>(bsums, nb);
  scan3_kernel<<<(N + 255) / 256, 256, 0, stream>>>(rowptr, bsums, cursor, N, E);
  scatter_kernel<<<(E + 255) / 256, 256, 0, stream>>>(esrc, edst, cursor, csr, E);

  int agg_blocks = (N * 64 + 255) / 256;           // one wave per node
  int ntm = (N + 63) / 64;
  int gemm_blocks = ntm * 2;                        // 2 column-halves
  int head_blocks = (N + 255) / 256;

  // layer 1
  aggregate_kernel<<<agg_blocks, 256, 0, stream>>>(x, rowptr, csr, bufA, N);
  gemm_tanh_kernel<<<gemm_blocks, 256, 0, stream>>>(bufA, W1, b1, bufB, N);
  // layer 2
  aggregate_kernel<<<agg_blocks, 256, 0, stream>>>(bufB, rowptr, csr, bufA, N);
  gemm_tanh_kernel<<<gemm_blocks, 256, 0, stream>>>(bufA, W2, b2, bufB, N);
  // head
  head_kernel<<<head_blocks, 256, 0, stream>>>(bufB, W3, b3, out, N);
}

// Round 3
// 434.925 us; speedup vs baseline: 36.4083x; 1.5563x over previous
//
#include <hip/hip_runtime.h>

#define DF 128
#define AST 136   // padded LDS row stride (bf16 elems): 272B, breaks 32-way banks

typedef float f32x4 __attribute__((ext_vector_type(4)));
typedef short bf16x8 __attribute__((ext_vector_type(8)));

__device__ __forceinline__ ushort f2bf(float f) {
  union { float f; uint u; } c; c.f = f;
  uint u = c.u;
  uint r = (u + 0x7fffu + ((u >> 16) & 1u)) >> 16;   // RNE
  return (ushort)r;
}
__device__ __forceinline__ float bf_lo(uint v) { union { uint u; float f; } c; c.u = v << 16; return c.f; }
__device__ __forceinline__ float bf_hi(uint v) { union { uint u; float f; } c; c.u = v & 0xffff0000u; return c.f; }

// ---------------- CSR build ----------------

__global__ void count_kernel(const int* __restrict__ dst, int* __restrict__ cnt, int E) {
  int i = blockIdx.x * blockDim.x + threadIdx.x;
  if (i < E) atomicAdd(&cnt[dst[i]], 1);
}

__global__ void scan1_kernel(const int* __restrict__ cnt, int* __restrict__ excl,
                             int* __restrict__ bsums, int n) {
  __shared__ int wsum[4];
  int t = threadIdx.x;
  int base = blockIdx.x * 1024 + t * 4;
  int v[4]; int s = 0;
#pragma unroll
  for (int i = 0; i < 4; i++) { int d = (base + i < n) ? cnt[base + i] : 0; v[i] = s; s += d; }
  int lane = t & 63, w = t >> 6;
  int sc = s;
#pragma unroll
  for (int off = 1; off < 64; off <<= 1) { int o = __shfl_up(sc, off); if (lane >= off) sc += o; }
  if (lane == 63) wsum[w] = sc;
  __syncthreads();
  int woff = 0;
  for (int i = 0; i < w; i++) woff += wsum[i];
  int toff = woff + (sc - s);
#pragma unroll
  for (int i = 0; i < 4; i++) if (base + i < n) excl[base + i] = toff + v[i];
  if (t == 255) bsums[blockIdx.x] = woff + sc;
}

__global__ void scan2_kernel(int* bsums, int nb) {
  if (threadIdx.x == 0 && blockIdx.x == 0) {
    int s = 0;
    for (int i = 0; i < nb; i++) { int d = bsums[i]; bsums[i] = s; s += d; }
  }
}

__global__ void scan3_kernel(int* __restrict__ rowptr, const int* __restrict__ bsums,
                             int* __restrict__ cursor, int n, int E) {
  int i = blockIdx.x * blockDim.x + threadIdx.x;
  if (i < n) {
    int v = rowptr[i] + bsums[i >> 10];
    rowptr[i] = v;
    cursor[i] = v;
  }
  if (i == 0) rowptr[n] = E;
}

__global__ void scatter_kernel(const int* __restrict__ src, const int* __restrict__ dst,
                               int* __restrict__ cursor, int* __restrict__ csr, int E) {
  int i = blockIdx.x * blockDim.x + threadIdx.x;
  if (i < E) {
    int pos = atomicAdd(&cursor[dst[i]], 1);
    csr[pos] = src[i];
  }
}

// ---------------- converts ----------------

__global__ void convert_bf16_kernel(const float* __restrict__ in, ushort* __restrict__ out, int n4) {
  int i = blockIdx.x * blockDim.x + threadIdx.x;
  if (i < n4) {
    float4 v = ((const float4*)in)[i];
    ushort4 o; o.x = f2bf(v.x); o.y = f2bf(v.y); o.z = f2bf(v.z); o.w = f2bf(v.w);
    ((ushort4*)out)[i] = o;
  }
}

// W [K=128][Nc] row-major f32 -> Wt [Ntc][128] bf16, rows >= Nc zero-padded
__global__ void transpose_w_kernel(const float* __restrict__ W, ushort* __restrict__ Wt,
                                   int Nc, int Ntc) {
  int i = blockIdx.x * blockDim.x + threadIdx.x;
  int total = Ntc * DF;
  if (i < total) {
    int nr = i >> 7;        // output row = column of W
    int k  = i & 127;
    float v = (nr < Nc) ? W[(size_t)k * Nc + nr] : 0.0f;
    Wt[i] = f2bf(v);
  }
}

// ---------------- scatter-mean as CSR gather: one wave per node, bf16 ----------------
__global__ void aggregate_kernel(const ushort* __restrict__ xb, const int* __restrict__ rowptr,
                                 const int* __restrict__ csr, ushort* __restrict__ out, int n) {
  int gw = (blockIdx.x * blockDim.x + threadIdx.x) >> 6;
  int lane = threadIdx.x & 63;
  if (gw >= n) return;
  int beg = rowptr[gw], end = rowptr[gw + 1];
  const uint* x2 = (const uint*)xb;          // 2 bf16 per lane (4B)
  float ax = 0.f, ay = 0.f;
  int e = beg;
  for (; e + 4 <= end; e += 4) {
    int s0 = csr[e], s1 = csr[e + 1], s2 = csr[e + 2], s3 = csr[e + 3];
    uint v0 = x2[(size_t)s0 * 64 + lane];
    uint v1 = x2[(size_t)s1 * 64 + lane];
    uint v2 = x2[(size_t)s2 * 64 + lane];
    uint v3 = x2[(size_t)s3 * 64 + lane];
    ax += bf_lo(v0) + bf_lo(v1) + bf_lo(v2) + bf_lo(v3);
    ay += bf_hi(v0) + bf_hi(v1) + bf_hi(v2) + bf_hi(v3);
  }
  for (; e < end; ++e) {
    uint v = x2[(size_t)csr[e] * 64 + lane];
    ax += bf_lo(v); ay += bf_hi(v);
  }
  int deg = end - beg;
  uint r;
  if (deg > 0) {
    float inv = 1.0f / (float)deg;
    r = (uint)f2bf(ax * inv) | ((uint)f2bf(ay * inv) << 16);
  } else {
    r = x2[(size_t)gw * 64 + lane];
  }
  ((uint*)out)[(size_t)gw * 64 + lane] = r;
}

// ---------------- GEMM [n x 128] @ W[128 x 128] + bias + tanh, bf16 MFMA ----------------
// Block: 64 nodes x 128 cols. 4 waves in 2x2: each wave 32 rows x 64 cols.
// mfma_f32_16x16x32_bf16: D = Afrag . Bfrag^T; both frags: row=lane&15, k=(lane>>4)*8+i.
// Bfrag rows = output cols -> W pre-transposed (Wt[n][k]).
// C/D: col=lane&15, row=(lane>>4)*4+reg  [m89-verified].
__global__ __launch_bounds__(256) void gemm_tanh_mfma(
    const ushort* __restrict__ A, const ushort* __restrict__ Wt,
    const float* __restrict__ bias, ushort* __restrict__ out, int n) {
  __shared__ ushort As[64 * AST];
  __shared__ ushort Ws[128 * AST];
  int tid = threadIdx.x;
  int node0 = blockIdx.x * 64;

  for (int i = tid; i < 64 * 16; i += 256) {       // A: 64 rows x 16 chunks of 8 bf16
    int r = i >> 4, c = i & 15;
    int node = node0 + r; if (node >= n) node = n - 1;
    uint4 v = ((const uint4*)(A + (size_t)node * DF))[c];
    *(uint4*)&As[r * AST + c * 8] = v;
  }
  for (int i = tid; i < 128 * 16; i += 256) {      // Wt: 128 rows x 16 chunks
    int r = i >> 4, c = i & 15;
    uint4 v = ((const uint4*)(Wt + r * DF))[c];
    *(uint4*)&Ws[r * AST + c * 8] = v;
  }
  __syncthreads();

  int lane = tid & 63, w = tid >> 6;
  int wr = (w >> 1) * 32;      // 0 / 32
  int wc = (w & 1) * 64;       // 0 / 64
  int r16 = lane & 15, g8 = (lane >> 4) * 8;

  f32x4 acc[2][4];
#pragma unroll
  for (int i = 0; i < 2; i++)
#pragma unroll
    for (int j = 0; j < 4; j++) acc[i][j] = (f32x4){0.f, 0.f, 0.f, 0.f};

#pragma unroll
  for (int ks = 0; ks < 4; ++ks) {
    int k0 = ks * 32 + g8;
    bf16x8 a0 = *(const bf16x8*)&As[(wr + r16) * AST + k0];
    bf16x8 a1 = *(const bf16x8*)&As[(wr + 16 + r16) * AST + k0];
#pragma unroll
    for (int j = 0; j < 4; j++) {
      bf16x8 b = *(const bf16x8*)&Ws[(wc + j * 16 + r16) * AST + k0];
      acc[0][j] = __builtin_amdgcn_mfma_f32_16x16x32_bf16(a0, b, acc[0][j], 0, 0, 0);
      acc[1][j] = __builtin_amdgcn_mfma_f32_16x16x32_bf16(a1, b, acc[1][j], 0, 0, 0);
    }
  }

#pragma unroll
  for (int mi = 0; mi < 2; mi++) {
#pragma unroll
    for (int j = 0; j < 4; j++) {
      int col = wc + j * 16 + r16;
      float bv = bias[col];
      int rowb = wr + mi * 16 + (lane >> 4) * 4;
#pragma unroll
      for (int q = 0; q < 4; q++) {
        int node = node0 + rowb + q;
        if (node < n) {
          float vv = tanhf(acc[mi][j][q] + bv);
          out[(size_t)node * DF + col] = f2bf(vv);
        }
      }
    }
  }
}

// ---------------- head: [n x 128] @ W3[128 x 10] + bias, bf16 MFMA, f32 out ----------------
// Block: 128 nodes, 4 waves; wave w: rows w*32 (2 m-frags), 16 cols (10 valid).
__global__ __launch_bounds__(256) void head_mfma(
    const ushort* __restrict__ A, const ushort* __restrict__ W3t,
    const float* __restrict__ bias, float* __restrict__ out, int n) {
  __shared__ ushort As[128 * AST];
  __shared__ ushort Ws[16 * AST];
  int tid = threadIdx.x;
  int node0 = blockIdx.x * 128;

  for (int i = tid; i < 128 * 16; i += 256) {
    int r = i >> 4, c = i & 15;
    int node = node0 + r; if (node >= n) node = n - 1;
    uint4 v = ((const uint4*)(A + (size_t)node * DF))[c];
    *(uint4*)&As[r * AST + c * 8] = v;
  }
  if (tid < 16 * 16) {
    int r = tid >> 4, c = tid & 15;
    uint4 v = ((const uint4*)(W3t + r * DF))[c];
    *(uint4*)&Ws[r * AST + c * 8] = v;
  }
  __syncthreads();

  int lane = tid & 63, w = tid >> 6;
  int r16 = lane & 15, g8 = (lane >> 4) * 8;
  f32x4 acc[2];
  acc[0] = (f32x4){0.f, 0.f, 0.f, 0.f};
  acc[1] = (f32x4){0.f, 0.f, 0.f, 0.f};

#pragma unroll
  for (int ks = 0; ks < 4; ++ks) {
    int k0 = ks * 32 + g8;
    bf16x8 b  = *(const bf16x8*)&Ws[r16 * AST + k0];
    bf16x8 a0 = *(const bf16x8*)&As[(w * 32 + r16) * AST + k0];
    bf16x8 a1 = *(const bf16x8*)&As[(w * 32 + 16 + r16) * AST + k0];
    acc[0] = __builtin_amdgcn_mfma_f32_16x16x32_bf16(a0, b, acc[0], 0, 0, 0);
    acc[1] = __builtin_amdgcn_mfma_f32_16x16x32_bf16(a1, b, acc[1], 0, 0, 0);
  }

  int col = r16;
  if (col < 10) {
    float bv = bias[col];
#pragma unroll
    for (int mi = 0; mi < 2; mi++) {
      int rowb = w * 32 + mi * 16 + (lane >> 4) * 4;
#pragma unroll
      for (int q = 0; q < 4; q++) {
        int node = node0 + rowb + q;
        if (node < n) out[(size_t)node * 10 + col] = acc[mi][q] + bv;
      }
    }
  }
}

extern "C" void kernel_launch(void* const* d_in, const int* in_sizes, int n_in,
                              void* d_out, int out_size, void* d_ws, size_t ws_size,
                              hipStream_t stream) {
  const float* x    = (const float*)d_in[0];
  const int*   esrc = (const int*)d_in[1];
  const int*   edst = (const int*)d_in[2];
  const float* W1   = (const float*)d_in[3];
  const float* b1   = (const float*)d_in[4];
  const float* W2   = (const float*)d_in[5];
  const float* b2   = (const float*)d_in[6];
  const float* W3   = (const float*)d_in[7];
  const float* b3   = (const float*)d_in[8];
  float* out = (float*)d_out;

  const int N = in_sizes[0] / DF;   // 100000
  const int E = in_sizes[1];        // 1600000

  // workspace: rowptr[N+1] | cursor[N] | bsums[1024] | csr[E] | xb | Wt1 | Wt2 | W3t | bufA | bufB
  char* ws = (char*)d_ws;
  int* rowptr = (int*)ws;
  int* cursor = rowptr + (N + 1);
  int* bsums  = cursor + N;
  int* csr    = bsums + 1024;
  size_t off = (size_t)((char*)(csr + E) - ws);
  off = (off + 255) & ~(size_t)255;
  ushort* xb  = (ushort*)(ws + off);                 off += (size_t)N * DF * 2; off = (off + 255) & ~(size_t)255;
  ushort* Wt1 = (ushort*)(ws + off);                 off += (size_t)DF * DF * 2;
  ushort* Wt2 = (ushort*)(ws + off);                 off += (size_t)DF * DF * 2;
  ushort* W3t = (ushort*)(ws + off);                 off += (size_t)16 * DF * 2; off = (off + 255) & ~(size_t)255;
  ushort* bufA = (ushort*)(ws + off);                off += (size_t)N * DF * 2; off = (off + 255) & ~(size_t)255;
  ushort* bufB = (ushort*)(ws + off);

  const int nb = (N + 1023) / 1024;

  hipMemsetAsync(cursor, 0, (size_t)N * sizeof(int), stream);
  count_kernel<<<(E + 255) / 256, 256, 0, stream>>>(edst, cursor, E);
  scan1_kernel<<<nb, 256, 0, stream>>>(cursor, rowptr, bsums, N);
  scan2_kernel<<<1, 64, 0, stream>>>(bsums, nb);
  scan3_kernel<<<(N + 255) / 256, 256, 0, stream>>>(rowptr, bsums, cursor, N, E);
  scatter_kernel<<<(E + 255) / 256, 256, 0, stream>>>(esrc, edst, cursor, csr, E);

  // converts (independent of CSR build; scheduler may overlap)
  int n4 = N * DF / 4;
  convert_bf16_kernel<<<(n4 + 255) / 256, 256, 0, stream>>>(x, xb, n4);
  transpose_w_kernel<<<(DF * DF + 255) / 256, 256, 0, stream>>>(W1, Wt1, DF, DF);
  transpose_w_kernel<<<(DF * DF + 255) / 256, 256, 0, stream>>>(W2, Wt2, DF, DF);
  transpose_w_kernel<<<(16 * DF + 255) / 256, 256, 0, stream>>>(W3, W3t, 10, 16);

  int agg_blocks = (N * 64 + 255) / 256;     // one wave per node
  int gemm_blocks = (N + 63) / 64;
  int head_blocks = (N + 127) / 128;

  // layer 1
  aggregate_kernel<<<agg_blocks, 256, 0, stream>>>(xb, rowptr, csr, bufA, N);
  gemm_tanh_mfma<<<gemm_blocks, 256, 0, stream>>>(bufA, Wt1, b1, bufB, N);
  // layer 2
  aggregate_kernel<<<agg_blocks, 256, 0, stream>>>(bufB, rowptr, csr, bufA, N);
  gemm_tanh_mfma<<<gemm_blocks, 256, 0, stream>>>(bufA, Wt2, b2, bufB, N);
  // head
  head_mfma<<<head_blocks, 256, 0, stream>>>(bufB, W3t, b3, out, N);
}

// Round 4
// 295.584 us; speedup vs baseline: 53.5714x; 1.4714x over previous
//
#include <hip/hip_runtime.h>

#define DF 128
#define AST 136   // padded LDS row stride (bf16 elems)
#define EPB 8192  // edges per block in bucket passes

typedef float f32x4 __attribute__((ext_vector_type(4)));
typedef short bf16x8 __attribute__((ext_vector_type(8)));

__device__ __forceinline__ ushort f2bf(float f) {
  union { float f; uint u; } c; c.f = f;
  uint u = c.u;
  uint r = (u + 0x7fffu + ((u >> 16) & 1u)) >> 16;   // RNE
  return (ushort)r;
}
__device__ __forceinline__ float bf_lo(uint v) { union { uint u; float f; } c; c.u = v << 16; return c.f; }
__device__ __forceinline__ float bf_hi(uint v) { union { uint u; float f; } c; c.u = v & 0xffff0000u; return c.f; }

// ---------------- CSR build: two-level counting sort ----------------
// bucket = dst >> 8 (256 nodes/bucket)

// Phase 1: per-block bucket histogram -> histG[b * nblocks + blk]
__global__ void bucket_hist_kernel(const int* __restrict__ dst, int* __restrict__ histG,
                                   int E, int nbuck, int nblocks) {
  extern __shared__ int lh[];
  int tid = threadIdx.x, blk = blockIdx.x;
  for (int i = tid; i < nbuck; i += 256) lh[i] = 0;
  __syncthreads();
  int base = blk * EPB;
#pragma unroll
  for (int it = 0; it < EPB / 256; ++it) {
    int e = base + it * 256 + tid;
    if (e < E) atomicAdd(&lh[dst[e] >> 8], 1);
  }
  __syncthreads();
  for (int i = tid; i < nbuck; i += 256) histG[i * nblocks + blk] = lh[i];
}

// generic scan (1024 elems/block)
__global__ void scan1_kernel(const int* __restrict__ cnt, int* __restrict__ excl,
                             int* __restrict__ bsums, int n) {
  __shared__ int wsum[4];
  int t = threadIdx.x;
  int base = blockIdx.x * 1024 + t * 4;
  int v[4]; int s = 0;
#pragma unroll
  for (int i = 0; i < 4; i++) { int d = (base + i < n) ? cnt[base + i] : 0; v[i] = s; s += d; }
  int lane = t & 63, w = t >> 6;
  int sc = s;
#pragma unroll
  for (int off = 1; off < 64; off <<= 1) { int o = __shfl_up(sc, off); if (lane >= off) sc += o; }
  if (lane == 63) wsum[w] = sc;
  __syncthreads();
  int woff = 0;
  for (int i = 0; i < w; i++) woff += wsum[i];
  int toff = woff + (sc - s);
#pragma unroll
  for (int i = 0; i < 4; i++) if (base + i < n) excl[base + i] = toff + v[i];
  if (t == 255) bsums[blockIdx.x] = woff + sc;
}

__global__ void scan2_kernel(int* bsums, int nb) {
  if (threadIdx.x == 0 && blockIdx.x == 0) {
    int s = 0;
    for (int i = 0; i < nb; i++) { int d = bsums[i]; bsums[i] = s; s += d; }
  }
}

__global__ void scan_add_kernel(const int* __restrict__ excl, const int* __restrict__ bsums,
                                int* __restrict__ out, int n) {
  int i = blockIdx.x * blockDim.x + threadIdx.x;
  if (i < n) out[i] = excl[i] + bsums[i >> 10];
}

// Phase 3: scatter edges into bucket-contiguous arrays via LDS cursors
__global__ void bucket_scatter_kernel(const int* __restrict__ src, const int* __restrict__ dst,
                                      const int* __restrict__ histS,
                                      int* __restrict__ eb_src, int* __restrict__ eb_dst,
                                      int E, int nbuck, int nblocks) {
  extern __shared__ int lc[];
  int tid = threadIdx.x, blk = blockIdx.x;
  for (int i = tid; i < nbuck; i += 256) lc[i] = histS[i * nblocks + blk];
  __syncthreads();
  int base = blk * EPB;
#pragma unroll
  for (int it = 0; it < EPB / 256; ++it) {
    int e = base + it * 256 + tid;
    if (e < E) {
      int d = dst[e];
      int pos = atomicAdd(&lc[d >> 8], 1);
      eb_src[pos] = src[e];
      eb_dst[pos] = d;
    }
  }
}

// Phase 4: one block per bucket -> counting sort over 256 nodes, emit rowptr + csr
__global__ void bucket_sort_kernel(const int* __restrict__ eb_src, const int* __restrict__ eb_dst,
                                   const int* __restrict__ histS,
                                   int* __restrict__ rowptr, int* __restrict__ csr,
                                   int N, int E, int nbuck, int nblocks) {
  __shared__ int cnt[256];
  __shared__ int cursor[256];
  __shared__ int wsum[4];
  int tid = threadIdx.x, b = blockIdx.x;
  int node0 = b << 8;
  int beg = histS[b * nblocks];
  int end = (b + 1 < nbuck) ? histS[(b + 1) * nblocks] : E;
  cnt[tid] = 0;
  __syncthreads();
  for (int e = beg + tid; e < end; e += 256)
    atomicAdd(&cnt[eb_dst[e] & 255], 1);
  __syncthreads();
  // exclusive scan of cnt[256]
  int v = cnt[tid];
  int lane = tid & 63, w = tid >> 6;
  int sc = v;
#pragma unroll
  for (int off = 1; off < 64; off <<= 1) { int o = __shfl_up(sc, off); if (lane >= off) sc += o; }
  if (lane == 63) wsum[w] = sc;
  __syncthreads();
  int woff = 0;
  for (int i = 0; i < w; i++) woff += wsum[i];
  int excl = woff + sc - v;
  int node = node0 + tid;
  if (node <= N) rowptr[node] = beg + excl;
  cursor[tid] = beg + excl;
  __syncthreads();
  for (int e = beg + tid; e < end; e += 256) {
    int d = eb_dst[e] & 255;
    int pos = atomicAdd(&cursor[d], 1);
    csr[pos] = eb_src[e];
  }
}

// ---------------- converts ----------------

__global__ void convert_bf16_kernel(const float* __restrict__ in, ushort* __restrict__ out, int n4) {
  int i = blockIdx.x * blockDim.x + threadIdx.x;
  if (i < n4) {
    float4 v = ((const float4*)in)[i];
    ushort4 o; o.x = f2bf(v.x); o.y = f2bf(v.y); o.z = f2bf(v.z); o.w = f2bf(v.w);
    ((ushort4*)out)[i] = o;
  }
}

// W [K=128][Nc] row-major f32 -> Wt [Ntc][128] bf16, rows >= Nc zero-padded
__global__ void transpose_w_kernel(const float* __restrict__ W, ushort* __restrict__ Wt,
                                   int Nc, int Ntc) {
  int i = blockIdx.x * blockDim.x + threadIdx.x;
  int total = Ntc * DF;
  if (i < total) {
    int nr = i >> 7;
    int k  = i & 127;
    float v = (nr < Nc) ? W[(size_t)k * Nc + nr] : 0.0f;
    Wt[i] = f2bf(v);
  }
}

// ---------------- scatter-mean as CSR gather: one wave per node, bf16 ----------------
__global__ void aggregate_kernel(const ushort* __restrict__ xb, const int* __restrict__ rowptr,
                                 const int* __restrict__ csr, ushort* __restrict__ out, int n) {
  int gw = (blockIdx.x * blockDim.x + threadIdx.x) >> 6;
  int lane = threadIdx.x & 63;
  if (gw >= n) return;
  int beg = rowptr[gw], end = rowptr[gw + 1];
  const uint* x2 = (const uint*)xb;          // 2 bf16 per lane (4B)
  float ax = 0.f, ay = 0.f;
  int e = beg;
  for (; e + 8 <= end; e += 8) {
    uint v0 = x2[(size_t)csr[e]     * 64 + lane];
    uint v1 = x2[(size_t)csr[e + 1] * 64 + lane];
    uint v2 = x2[(size_t)csr[e + 2] * 64 + lane];
    uint v3 = x2[(size_t)csr[e + 3] * 64 + lane];
    uint v4 = x2[(size_t)csr[e + 4] * 64 + lane];
    uint v5 = x2[(size_t)csr[e + 5] * 64 + lane];
    uint v6 = x2[(size_t)csr[e + 6] * 64 + lane];
    uint v7 = x2[(size_t)csr[e + 7] * 64 + lane];
    ax += (bf_lo(v0) + bf_lo(v1)) + (bf_lo(v2) + bf_lo(v3)) + (bf_lo(v4) + bf_lo(v5)) + (bf_lo(v6) + bf_lo(v7));
    ay += (bf_hi(v0) + bf_hi(v1)) + (bf_hi(v2) + bf_hi(v3)) + (bf_hi(v4) + bf_hi(v5)) + (bf_hi(v6) + bf_hi(v7));
  }
  for (; e < end; ++e) {
    uint v = x2[(size_t)csr[e] * 64 + lane];
    ax += bf_lo(v); ay += bf_hi(v);
  }
  int deg = end - beg;
  uint r;
  if (deg > 0) {
    float inv = 1.0f / (float)deg;
    r = (uint)f2bf(ax * inv) | ((uint)f2bf(ay * inv) << 16);
  } else {
    r = x2[(size_t)gw * 64 + lane];
  }
  ((uint*)out)[(size_t)gw * 64 + lane] = r;
}

// ---------------- GEMM [n x 128] @ W[128 x 128] + bias + tanh, bf16 MFMA ----------------
__global__ __launch_bounds__(256) void gemm_tanh_mfma(
    const ushort* __restrict__ A, const ushort* __restrict__ Wt,
    const float* __restrict__ bias, ushort* __restrict__ out, int n) {
  __shared__ ushort As[64 * AST];
  __shared__ ushort Ws[128 * AST];
  int tid = threadIdx.x;
  int node0 = blockIdx.x * 64;

  for (int i = tid; i < 64 * 16; i += 256) {
    int r = i >> 4, c = i & 15;
    int node = node0 + r; if (node >= n) node = n - 1;
    uint4 v = ((const uint4*)(A + (size_t)node * DF))[c];
    *(uint4*)&As[r * AST + c * 8] = v;
  }
  for (int i = tid; i < 128 * 16; i += 256) {
    int r = i >> 4, c = i & 15;
    uint4 v = ((const uint4*)(Wt + r * DF))[c];
    *(uint4*)&Ws[r * AST + c * 8] = v;
  }
  __syncthreads();

  int lane = tid & 63, w = tid >> 6;
  int wr = (w >> 1) * 32;
  int wc = (w & 1) * 64;
  int r16 = lane & 15, g8 = (lane >> 4) * 8;

  f32x4 acc[2][4];
#pragma unroll
  for (int i = 0; i < 2; i++)
#pragma unroll
    for (int j = 0; j < 4; j++) acc[i][j] = (f32x4){0.f, 0.f, 0.f, 0.f};

#pragma unroll
  for (int ks = 0; ks < 4; ++ks) {
    int k0 = ks * 32 + g8;
    bf16x8 a0 = *(const bf16x8*)&As[(wr + r16) * AST + k0];
    bf16x8 a1 = *(const bf16x8*)&As[(wr + 16 + r16) * AST + k0];
#pragma unroll
    for (int j = 0; j < 4; j++) {
      bf16x8 b = *(const bf16x8*)&Ws[(wc + j * 16 + r16) * AST + k0];
      acc[0][j] = __builtin_amdgcn_mfma_f32_16x16x32_bf16(a0, b, acc[0][j], 0, 0, 0);
      acc[1][j] = __builtin_amdgcn_mfma_f32_16x16x32_bf16(a1, b, acc[1][j], 0, 0, 0);
    }
  }

#pragma unroll
  for (int mi = 0; mi < 2; mi++) {
#pragma unroll
    for (int j = 0; j < 4; j++) {
      int col = wc + j * 16 + r16;
      float bv = bias[col];
      int rowb = wr + mi * 16 + (lane >> 4) * 4;
#pragma unroll
      for (int q = 0; q < 4; q++) {
        int node = node0 + rowb + q;
        if (node < n) {
          float vv = tanhf(acc[mi][j][q] + bv);
          out[(size_t)node * DF + col] = f2bf(vv);
        }
      }
    }
  }
}

// ---------------- head: [n x 128] @ W3[128 x 10] + bias, bf16 MFMA, f32 out ----------------
__global__ __launch_bounds__(256) void head_mfma(
    const ushort* __restrict__ A, const ushort* __restrict__ W3t,
    const float* __restrict__ bias, float* __restrict__ out, int n) {
  __shared__ ushort As[128 * AST];
  __shared__ ushort Ws[16 * AST];
  int tid = threadIdx.x;
  int node0 = blockIdx.x * 128;

  for (int i = tid; i < 128 * 16; i += 256) {
    int r = i >> 4, c = i & 15;
    int node = node0 + r; if (node >= n) node = n - 1;
    uint4 v = ((const uint4*)(A + (size_t)node * DF))[c];
    *(uint4*)&As[r * AST + c * 8] = v;
  }
  if (tid < 16 * 16) {
    int r = tid >> 4, c = tid & 15;
    uint4 v = ((const uint4*)(W3t + r * DF))[c];
    *(uint4*)&Ws[r * AST + c * 8] = v;
  }
  __syncthreads();

  int lane = tid & 63, w = tid >> 6;
  int r16 = lane & 15, g8 = (lane >> 4) * 8;
  f32x4 acc[2];
  acc[0] = (f32x4){0.f, 0.f, 0.f, 0.f};
  acc[1] = (f32x4){0.f, 0.f, 0.f, 0.f};

#pragma unroll
  for (int ks = 0; ks < 4; ++ks) {
    int k0 = ks * 32 + g8;
    bf16x8 b  = *(const bf16x8*)&Ws[r16 * AST + k0];
    bf16x8 a0 = *(const bf16x8*)&As[(w * 32 + r16) * AST + k0];
    bf16x8 a1 = *(const bf16x8*)&As[(w * 32 + 16 + r16) * AST + k0];
    acc[0] = __builtin_amdgcn_mfma_f32_16x16x32_bf16(a0, b, acc[0], 0, 0, 0);
    acc[1] = __builtin_amdgcn_mfma_f32_16x16x32_bf16(a1, b, acc[1], 0, 0, 0);
  }

  int col = r16;
  if (col < 10) {
    float bv = bias[col];
#pragma unroll
    for (int mi = 0; mi < 2; mi++) {
      int rowb = w * 32 + mi * 16 + (lane >> 4) * 4;
#pragma unroll
      for (int q = 0; q < 4; q++) {
        int node = node0 + rowb + q;
        if (node < n) out[(size_t)node * 10 + col] = acc[mi][q] + bv;
      }
    }
  }
}

extern "C" void kernel_launch(void* const* d_in, const int* in_sizes, int n_in,
                              void* d_out, int out_size, void* d_ws, size_t ws_size,
                              hipStream_t stream) {
  const float* x    = (const float*)d_in[0];
  const int*   esrc = (const int*)d_in[1];
  const int*   edst = (const int*)d_in[2];
  const float* W1   = (const float*)d_in[3];
  const float* b1   = (const float*)d_in[4];
  const float* W2   = (const float*)d_in[5];
  const float* b2   = (const float*)d_in[6];
  const float* W3   = (const float*)d_in[7];
  const float* b3   = (const float*)d_in[8];
  float* out = (float*)d_out;

  const int N = in_sizes[0] / DF;   // 100000
  const int E = in_sizes[1];        // 1600000

  const int nbuck   = (N + 255) >> 8;            // 391
  const int nblocks = (E + EPB - 1) / EPB;       // 196
  const int M = nbuck * nblocks;                 // ~76.6K

  // workspace layout
  char* ws = (char*)d_ws;
  int* rowptr = (int*)ws;                // N+1
  int* csr    = rowptr + (N + 1);        // E
  int* histG  = csr + E;                 // M
  int* histE  = histG + M;               // M
  int* histS  = histE + M;               // M
  int* bsums2 = histS + M;               // 1024
  int* eb_src = bsums2 + 1024;           // E
  int* eb_dst = eb_src + E;              // E
  size_t off = (size_t)((char*)(eb_dst + E) - ws);
  off = (off + 255) & ~(size_t)255;
  ushort* xb  = (ushort*)(ws + off);     off += (size_t)N * DF * 2; off = (off + 255) & ~(size_t)255;
  ushort* Wt1 = (ushort*)(ws + off);     off += (size_t)DF * DF * 2;
  ushort* Wt2 = (ushort*)(ws + off);     off += (size_t)DF * DF * 2;
  ushort* W3t = (ushort*)(ws + off);     off += (size_t)16 * DF * 2; off = (off + 255) & ~(size_t)255;
  ushort* bufA = (ushort*)(ws + off);    off += (size_t)N * DF * 2; off = (off + 255) & ~(size_t)255;
  ushort* bufB = (ushort*)(ws + off);

  // converts
  int n4 = N * DF / 4;
  convert_bf16_kernel<<<(n4 + 255) / 256, 256, 0, stream>>>(x, xb, n4);
  transpose_w_kernel<<<(DF * DF + 255) / 256, 256, 0, stream>>>(W1, Wt1, DF, DF);
  transpose_w_kernel<<<(DF * DF + 255) / 256, 256, 0, stream>>>(W2, Wt2, DF, DF);
  transpose_w_kernel<<<(16 * DF + 255) / 256, 256, 0, stream>>>(W3, W3t, 10, 16);

  // CSR build
  size_t lds_b = (size_t)nbuck * sizeof(int);
  bucket_hist_kernel<<<nblocks, 256, lds_b, stream>>>(edst, histG, E, nbuck, nblocks);
  int nb_m = (M + 1023) / 1024;
  scan1_kernel<<<nb_m, 256, 0, stream>>>(histG, histE, bsums2, M);
  scan2_kernel<<<1, 64, 0, stream>>>(bsums2, nb_m);
  scan_add_kernel<<<(M + 255) / 256, 256, 0, stream>>>(histE, bsums2, histS, M);
  bucket_scatter_kernel<<<nblocks, 256, lds_b, stream>>>(esrc, edst, histS, eb_src, eb_dst, E, nbuck, nblocks);
  bucket_sort_kernel<<<nbuck, 256, 0, stream>>>(eb_src, eb_dst, histS, rowptr, csr, N, E, nbuck, nblocks);

  int agg_blocks = (N * 64 + 255) / 256;
  int gemm_blocks = (N + 63) / 64;
  int head_blocks = (N + 127) / 128;

  // layer 1
  aggregate_kernel<<<agg_blocks, 256, 0, stream>>>(xb, rowptr, csr, bufA, N);
  gemm_tanh_mfma<<<gemm_blocks, 256, 0, stream>>>(bufA, Wt1, b1, bufB, N);
  // layer 2
  aggregate_kernel<<<agg_blocks, 256, 0, stream>>>(bufB, rowptr, csr, bufA, N);
  gemm_tanh_mfma<<<gemm_blocks, 256, 0, stream>>>(bufA, Wt2, b2, bufB, N);
  // head
  head_mfma<<<head_blocks, 256, 0, stream>>>(bufB, W3t, b3, out, N);
}